// Round 12
// baseline (311.546 us; speedup 1.0000x reference)
//
#include <hip/hip_runtime.h>

#define B_ 256
#define K_ 10
#define I_ 1152
#define O_ 16
#define C_ 8
#define BKO (B_*K_*O_)   // 40960

static __device__ __forceinline__ unsigned short f32_bf16(float f) {
    unsigned int u = __float_as_uint(f);
    u += 0x7FFFu + ((u >> 16) & 1u);           // round-to-nearest-even
    return (unsigned short)(u >> 16);
}

// DPP butterfly add step (full-rate VALU; ctrl must be a compile-time const)
template <int CTRL>
static __device__ __forceinline__ float dpp_add(float v) {
    int x = __builtin_amdgcn_update_dpp(0, __float_as_int(v), CTRL, 0xF, 0xF, true);
    return v + __int_as_float(x);
}
// sum over the 16 lanes of each DPP row: xor1, xor2, half-mirror, mirror
static __device__ __forceinline__ float row16_sum(float v) {
    v = dpp_add<0xB1>(v);     // quad_perm(1,0,3,2)  : + lane^1
    v = dpp_add<0x4E>(v);     // quad_perm(2,3,0,1)  : + lane^2
    v = dpp_add<0x141>(v);    // row_half_mirror     : + other quad
    v = dpp_add<0x140>(v);    // row_mirror          : + other half-row
    return v;
}

// ---------------------------------------------------------------------------
// uhat_kernel v4: u[b][k][i][o] = bf16(w·x)  AND  s1[b,k,o] += sum_i u (f32).
// grid (72, 4, 5); 256 thr; 4 b per thread (ds_read amortized 4x).
// Pass-1 fold: per (oq,half) group the 8 f32 d-values are row16-reduced over
// the block's 16 i-lanes via DPP (VALU pipe) and one lane per row atomicAdds
// them into s1 (memset-zeroed).  This removes route's pass-1 u sweep (94 MB).
// ---------------------------------------------------------------------------
__global__ __launch_bounds__(256) void uhat_kernel(
    const float* __restrict__ x, const float* __restrict__ w,
    unsigned short* __restrict__ u, float* __restrict__ s1)
{
    __shared__ float w_lds[16 * 132];   // [ii][o*8+c], stride 132: 2-way max
    const int t   = threadIdx.x;
    const int i_l = t & 15, tg = t >> 4;
    const int i0  = blockIdx.x * 16;
    const int b0  = blockIdx.y * 64 + tg * 4;
    const int kb  = blockIdx.z * 2;
    const int i   = i0 + i_l;
    const bool row_leader = (i_l == 0);

    float4 xr[4][2];
#pragma unroll
    for (int bb = 0; bb < 4; bb++) {
        const float4* xp = (const float4*)(x + ((size_t)(b0 + bb) * I_ + i) * C_);
        xr[bb][0] = xp[0];
        xr[bb][1] = xp[1];
    }

#pragma unroll
    for (int kk = 0; kk < 2; kk++) {
        const int k = kb + kk;
        __syncthreads();
        const float4* ws = (const float4*)(w + ((size_t)k * I_ + i0) * O_ * C_);
#pragma unroll
        for (int r = 0; r < 2; r++) {
            int idx = r * 256 + t;               // float4 index in 16x128 slab
            int ii = idx >> 5, rem = idx & 31;
            *(float4*)&w_lds[ii * 132 + rem * 4] = ws[idx];
        }
        __syncthreads();

#pragma unroll
        for (int half = 0; half < 2; half++) {   // o 0..7 then 8..15
            unsigned int pk[4][4];
#pragma unroll
            for (int oq = 0; oq < 4; oq++) {
                const int oo = half * 4 + oq;    // o-pair index
                float d[4][2];
#pragma unroll
                for (int h = 0; h < 2; h++) {
                    const int o = oo * 2 + h;
                    const float4 w0 = *(const float4*)&w_lds[i_l * 132 + o * 8];
                    const float4 w1 = *(const float4*)&w_lds[i_l * 132 + o * 8 + 4];
#pragma unroll
                    for (int bb = 0; bb < 4; bb++) {
                        d[bb][h] = w0.x*xr[bb][0].x + w0.y*xr[bb][0].y
                                 + w0.z*xr[bb][0].z + w0.w*xr[bb][0].w
                                 + w1.x*xr[bb][1].x + w1.y*xr[bb][1].y
                                 + w1.z*xr[bb][1].z + w1.w*xr[bb][1].w;
                    }
                }
                // pass-1 fold: i-sum via DPP, leader lane accumulates to s1
#pragma unroll
                for (int bb = 0; bb < 4; bb++) {
#pragma unroll
                    for (int h = 0; h < 2; h++) {
                        const float rs = row16_sum(d[bb][h]);
                        if (row_leader)
                            atomicAdd(&s1[((size_t)(b0 + bb) * K_ + k) * O_
                                          + oo * 2 + h], rs);
                    }
                }
#pragma unroll
                for (int bb = 0; bb < 4; bb++)
                    pk[bb][oq] = (unsigned int)f32_bf16(d[bb][0]) |
                                 ((unsigned int)f32_bf16(d[bb][1]) << 16);
            }
#pragma unroll
            for (int bb = 0; bb < 4; bb++) {
                unsigned int* dst = (unsigned int*)
                    (u + (((size_t)(b0 + bb) * K_ + k) * I_ + i) * O_) + half * 4;
                *(uint4*)dst = make_uint4(pk[bb][0], pk[bb][1], pk[bb][2], pk[bb][3]);
            }
        }
    }
}

// ---------------------------------------------------------------------------
// sweep (o-pair mapping, 1024-thr block): one routing pass over all i.
// thread: og = t&7 (owns o = og*2, og*2+1), i_l = t>>3 in [0,128); 9 chunks.
// No max-subtraction: |logit| = |sum_16 u*v| is tiny, exp safe in f32.
// ---------------------------------------------------------------------------
static __device__ __forceinline__ void sweep(
    const unsigned short* __restrict__ ub, int i_l,
    const float* __restrict__ v_lds, int og, float acc[K_][2])
{
#pragma unroll
    for (int k = 0; k < K_; k++) { acc[k][0] = 0.f; acc[k][1] = 0.f; }

    unsigned int P[K_], Q[K_];
#pragma unroll
    for (int k = 0; k < K_; k++)
        P[k] = *(const unsigned int*)(ub + ((size_t)k * I_ + i_l) * O_);

#pragma unroll 1                          // keep regs low; body is big enough
    for (int ic = 0; ic < 9; ic++) {
        if (ic + 1 < 9) {
            const int i = (ic + 1) * 128 + i_l;
#pragma unroll
            for (int k = 0; k < K_; k++)
                Q[k] = *(const unsigned int*)(ub + ((size_t)k * I_ + i) * O_);
        }
        float c[K_];
        float Z = 0.f;
#pragma unroll
        for (int k = 0; k < K_; k++) {
            const float f0 = __uint_as_float(P[k] << 16);
            const float f1 = __uint_as_float(P[k] & 0xffff0000u);
            float lk = f0 * v_lds[k * 16 + og * 2]
                     + f1 * v_lds[k * 16 + og * 2 + 1];
            lk += __shfl_xor(lk, 1);
            lk += __shfl_xor(lk, 2);
            lk += __shfl_xor(lk, 4);
            c[k] = __expf(lk);
            Z += c[k];
        }
        const float inv = 1.0f / Z;
#pragma unroll
        for (int k = 0; k < K_; k++) {
            const float ck = c[k] * inv;
            const float f0 = __uint_as_float(P[k] << 16);
            const float f1 = __uint_as_float(P[k] & 0xffff0000u);
            acc[k][0] = fmaf(ck, f0, acc[k][0]);
            acc[k][1] = fmaf(ck, f1, acc[k][1]);
        }
#pragma unroll
        for (int k = 0; k < K_; k++) P[k] = Q[k];
    }
}

// reduce acc over the 8 i-positions of each wave; deposit per-wave sums.
static __device__ __forceinline__ void block_reduce(
    float acc[K_][2], float* __restrict__ red, int lane, int wv)
{
#pragma unroll
    for (int k = 0; k < K_; k++)
#pragma unroll
        for (int j = 0; j < 2; j++) {
            float a = acc[k][j];
            a += __shfl_xor(a, 8); a += __shfl_xor(a, 16); a += __shfl_xor(a, 32);
            acc[k][j] = a;
        }
    if (lane < 8) {
#pragma unroll
        for (int k = 0; k < K_; k++)
            *(float2*)&red[wv * 160 + k * 16 + lane * 2] =
                make_float2(acc[k][0], acc[k][1]);
    }
    __syncthreads();
}

// sum the 16 per-wave partials for element t (t < 160)
static __device__ __forceinline__ float sum16(const float* __restrict__ red, int t)
{
    float s = 0.f;
#pragma unroll
    for (int wgi = 0; wgi < 16; wgi++) s += red[wgi * 160 + t];
    return s;
}

// squash for element t<160: 16-lane o-group norm reduce
static __device__ __forceinline__ float squash_v(float s) {
    float n2 = s * s;
    n2 += __shfl_xor(n2, 1); n2 += __shfl_xor(n2, 2);
    n2 += __shfl_xor(n2, 4); n2 += __shfl_xor(n2, 8);
    const float norm = sqrtf(n2);
    return s * (n2 / (1.0f + n2) / (norm + 1e-9f));
}

// ---------------------------------------------------------------------------
// route_all v4: passes 2+3 only (pass 1 pre-reduced into s1 by uhat).
// grid (256), 1024 thr.  Prologue: v1 = squash(s1/K).  Then 2 u sweeps
// instead of 3 -> logical traffic 283 -> 189 MB (the round-9/10 invariant).
// ---------------------------------------------------------------------------
__global__ __launch_bounds__(1024) void route_all(
    const unsigned short* __restrict__ u, const float* __restrict__ s1,
    float* __restrict__ out)
{
    __shared__ float red[16 * 160];
    __shared__ float v_lds[160];
    __shared__ float v1_lds[160];

    const int t    = threadIdx.x;
    const int og   = t & 7, i_l = t >> 3;   // og: o-pair, i_l in 0..127
    const int b    = blockIdx.x;
    const int lane = t & 63, wv = t >> 6;

    const unsigned short* ub = u + (size_t)b * K_ * I_ * O_ + og * 2;
    float acc[K_][2];

    // ---- prologue: v1 from precomputed s1 ----
    if (t < 160) {
        float v = squash_v(s1[(size_t)b * 160 + t] * (1.0f / K_));
        v1_lds[t] = v;
        v_lds[t]  = v;
    }
    __syncthreads();

    // ---- pass 2: logits from v1 ----
    sweep(ub, i_l, v_lds, og, acc);
    block_reduce(acc, red, lane, wv);
    float v12 = 0.f;
    if (t < 160) v12 = v1_lds[t] + squash_v(sum16(red, t));
    __syncthreads();          // all sum16 reads done before v_lds overwrite
    if (t < 160) v_lds[t] = v12;
    __syncthreads();

    // ---- pass 3: logits from v1+v2 (telescoped) ----
    sweep(ub, i_l, v_lds, og, acc);
    block_reduce(acc, red, lane, wv);
    if (t < 160)
        out[(size_t)b * 160 + t] = squash_v(sum16(red, t));
}

// ---------------------------------------------------------------------------
extern "C" void kernel_launch(void* const* d_in, const int* in_sizes, int n_in,
                              void* d_out, int out_size, void* d_ws, size_t ws_size,
                              hipStream_t stream)
{
    const float* x = (const float*)d_in[0];
    const float* w = (const float*)d_in[1];
    float* outp = (float*)d_out;

    float* s1 = (float*)d_ws;                           // BKO f32 = 160 KB
    unsigned short* u = (unsigned short*)(s1 + BKO);    // B*K*I*O bf16 = 94.4 MB

    (void)hipMemsetAsync(s1, 0, (size_t)BKO * sizeof(float), stream);
    uhat_kernel<<<dim3(72, 4, 5), 256, 0, stream>>>(x, w, u, s1);
    route_all<<<B_, 1024, 0, stream>>>(u, s1, outp);
}

// Round 13
// 138.932 us; speedup vs baseline: 2.2424x; 2.2424x over previous
//
#include <hip/hip_runtime.h>

#define B_ 256
#define K_ 10
#define I_ 1152
#define O_ 16
#define C_ 8
#define BKO (B_*K_*O_)   // 40960
#define NX 72            // i0 blocks (uhat grid.x)

static __device__ __forceinline__ unsigned short f32_bf16(float f) {
    unsigned int u = __float_as_uint(f);
    u += 0x7FFFu + ((u >> 16) & 1u);           // round-to-nearest-even
    return (unsigned short)(u >> 16);
}

// DPP butterfly add step (full-rate VALU; ctrl is a compile-time const)
template <int CTRL>
static __device__ __forceinline__ float dpp_add(float v) {
    int x = __builtin_amdgcn_update_dpp(0, __float_as_int(v), CTRL, 0xF, 0xF, true);
    return v + __int_as_float(x);
}
// sum over each 16-lane DPP row: xor1, xor2, half-mirror, mirror
static __device__ __forceinline__ float row16_sum(float v) {
    v = dpp_add<0xB1>(v);     // quad_perm(1,0,3,2)  : + lane^1
    v = dpp_add<0x4E>(v);     // quad_perm(2,3,0,1)  : + lane^2
    v = dpp_add<0x141>(v);    // row_half_mirror     : + other quad
    v = dpp_add<0x140>(v);    // row_mirror          : + other half-row
    return v;
}

// ---------------------------------------------------------------------------
// uhat_kernel v5: u[b][k][i][o] = bf16(w·x)  AND per-block i-partials of
// pass 1 into part[x][b][k][o]  (NO atomics — round-12's 2.9M device atomics
// cost 180 µs; this uses DPP row-sum -> LDS -> one dense coalesced store).
// grid (72, 4, 5); 256 thr; 4 b per thread (ds_read amortized 4x).
// ---------------------------------------------------------------------------
__global__ __launch_bounds__(256) void uhat_kernel(
    const float* __restrict__ x, const float* __restrict__ w,
    unsigned short* __restrict__ u, float* __restrict__ part)
{
    __shared__ float w_lds[16 * 132];   // [ii][o*8+c], stride 132: 2-way max
    __shared__ float p_lds[2][64 * 16]; // [kk][b_local*16 + o] pass-1 partials
    const int t   = threadIdx.x;
    const int i_l = t & 15, tg = t >> 4;
    const int i0  = blockIdx.x * 16;
    const int b0  = blockIdx.y * 64 + tg * 4;
    const int kb  = blockIdx.z * 2;
    const int i   = i0 + i_l;
    const bool row_leader = (i_l == 0);

    float4 xr[4][2];
#pragma unroll
    for (int bb = 0; bb < 4; bb++) {
        const float4* xp = (const float4*)(x + ((size_t)(b0 + bb) * I_ + i) * C_);
        xr[bb][0] = xp[0];
        xr[bb][1] = xp[1];
    }

#pragma unroll
    for (int kk = 0; kk < 2; kk++) {
        const int k = kb + kk;
        __syncthreads();
        const float4* ws = (const float4*)(w + ((size_t)k * I_ + i0) * O_ * C_);
#pragma unroll
        for (int r = 0; r < 2; r++) {
            int idx = r * 256 + t;               // float4 index in 16x128 slab
            int ii = idx >> 5, rem = idx & 31;
            *(float4*)&w_lds[ii * 132 + rem * 4] = ws[idx];
        }
        __syncthreads();

#pragma unroll
        for (int half = 0; half < 2; half++) {   // o 0..7 then 8..15
            unsigned int pk[4][4];
#pragma unroll
            for (int oq = 0; oq < 4; oq++) {
                const int oo = half * 4 + oq;    // o-pair index
                float d[4][2];
#pragma unroll
                for (int h = 0; h < 2; h++) {
                    const int o = oo * 2 + h;
                    const float4 w0 = *(const float4*)&w_lds[i_l * 132 + o * 8];
                    const float4 w1 = *(const float4*)&w_lds[i_l * 132 + o * 8 + 4];
#pragma unroll
                    for (int bb = 0; bb < 4; bb++) {
                        d[bb][h] = w0.x*xr[bb][0].x + w0.y*xr[bb][0].y
                                 + w0.z*xr[bb][0].z + w0.w*xr[bb][0].w
                                 + w1.x*xr[bb][1].x + w1.y*xr[bb][1].y
                                 + w1.z*xr[bb][1].z + w1.w*xr[bb][1].w;
                    }
                }
                // pass-1 fold: i-sum via DPP rows (16 lanes = the 16 i's)
#pragma unroll
                for (int bb = 0; bb < 4; bb++) {
#pragma unroll
                    for (int h = 0; h < 2; h++) {
                        const float rs = row16_sum(d[bb][h]);
                        if (row_leader)
                            p_lds[kk][(tg * 4 + bb) * 16 + oo * 2 + h] = rs;
                    }
                }
#pragma unroll
                for (int bb = 0; bb < 4; bb++)
                    pk[bb][oq] = (unsigned int)f32_bf16(d[bb][0]) |
                                 ((unsigned int)f32_bf16(d[bb][1]) << 16);
            }
#pragma unroll
            for (int bb = 0; bb < 4; bb++) {
                unsigned int* dst = (unsigned int*)
                    (u + (((size_t)(b0 + bb) * K_ + k) * I_ + i) * O_) + half * 4;
                *(uint4*)dst = make_uint4(pk[bb][0], pk[bb][1], pk[bb][2], pk[bb][3]);
            }
        }
    }

    // dense partial store: part[x][b][k][o], addr = ((x*256+b)*10 + k)*16 + o
    __syncthreads();
    {
        const int bl = t >> 2, o4 = (t & 3) * 4;     // b_local, o-quad
        const int b  = blockIdx.y * 64 + bl;
#pragma unroll
        for (int kk = 0; kk < 2; kk++) {
            const float4 val = *(const float4*)&p_lds[kk][t * 4];  // = [bl*16+o4]
            *(float4*)&part[(((size_t)blockIdx.x * 256 + b) * K_ + kb + kk) * O_ + o4] = val;
        }
    }
}

// ---------------------------------------------------------------------------
// sweep (o-pair mapping, 1024-thr block): one routing pass over all i.
// thread: og = t&7 (owns o = og*2, og*2+1), i_l = t>>3 in [0,128); 9 chunks.
// No max-subtraction: |logit| = |sum_16 u*v| is tiny, exp safe in f32.
// ---------------------------------------------------------------------------
static __device__ __forceinline__ void sweep(
    const unsigned short* __restrict__ ub, int i_l,
    const float* __restrict__ v_lds, int og, float acc[K_][2])
{
#pragma unroll
    for (int k = 0; k < K_; k++) { acc[k][0] = 0.f; acc[k][1] = 0.f; }

    unsigned int P[K_], Q[K_];
#pragma unroll
    for (int k = 0; k < K_; k++)
        P[k] = *(const unsigned int*)(ub + ((size_t)k * I_ + i_l) * O_);

#pragma unroll 1                          // keep regs low; body is big enough
    for (int ic = 0; ic < 9; ic++) {
        if (ic + 1 < 9) {
            const int i = (ic + 1) * 128 + i_l;
#pragma unroll
            for (int k = 0; k < K_; k++)
                Q[k] = *(const unsigned int*)(ub + ((size_t)k * I_ + i) * O_);
        }
        float c[K_];
        float Z = 0.f;
#pragma unroll
        for (int k = 0; k < K_; k++) {
            const float f0 = __uint_as_float(P[k] << 16);
            const float f1 = __uint_as_float(P[k] & 0xffff0000u);
            float lk = f0 * v_lds[k * 16 + og * 2]
                     + f1 * v_lds[k * 16 + og * 2 + 1];
            lk += __shfl_xor(lk, 1);
            lk += __shfl_xor(lk, 2);
            lk += __shfl_xor(lk, 4);
            c[k] = __expf(lk);
            Z += c[k];
        }
        const float inv = 1.0f / Z;
#pragma unroll
        for (int k = 0; k < K_; k++) {
            const float ck = c[k] * inv;
            const float f0 = __uint_as_float(P[k] << 16);
            const float f1 = __uint_as_float(P[k] & 0xffff0000u);
            acc[k][0] = fmaf(ck, f0, acc[k][0]);
            acc[k][1] = fmaf(ck, f1, acc[k][1]);
        }
#pragma unroll
        for (int k = 0; k < K_; k++) P[k] = Q[k];
    }
}

// reduce acc over the 8 i-positions of each wave; deposit per-wave sums.
static __device__ __forceinline__ void block_reduce(
    float acc[K_][2], float* __restrict__ red, int lane, int wv)
{
#pragma unroll
    for (int k = 0; k < K_; k++)
#pragma unroll
        for (int j = 0; j < 2; j++) {
            float a = acc[k][j];
            a += __shfl_xor(a, 8); a += __shfl_xor(a, 16); a += __shfl_xor(a, 32);
            acc[k][j] = a;
        }
    if (lane < 8) {
#pragma unroll
        for (int k = 0; k < K_; k++)
            *(float2*)&red[wv * 160 + k * 16 + lane * 2] =
                make_float2(acc[k][0], acc[k][1]);
    }
    __syncthreads();
}

// sum the 16 per-wave partials for element t (t < 160)
static __device__ __forceinline__ float sum16(const float* __restrict__ red, int t)
{
    float s = 0.f;
#pragma unroll
    for (int wgi = 0; wgi < 16; wgi++) s += red[wgi * 160 + t];
    return s;
}

// squash for element t<160: 16-lane o-group norm reduce
static __device__ __forceinline__ float squash_v(float s) {
    float n2 = s * s;
    n2 += __shfl_xor(n2, 1); n2 += __shfl_xor(n2, 2);
    n2 += __shfl_xor(n2, 4); n2 += __shfl_xor(n2, 8);
    const float norm = sqrtf(n2);
    return s * (n2 / (1.0f + n2) / (norm + 1e-9f));
}

// ---------------------------------------------------------------------------
// route_all v5: passes 2+3 only; pass 1 comes from the part tensor.
// grid (256), 1024 thr.  Prologue: s1 = sum_x part[x][b], v1 = squash(s1/K).
// 2 u sweeps instead of 3 -> logical u traffic 283 -> 189 MB.
// ---------------------------------------------------------------------------
__global__ __launch_bounds__(1024) void route_all(
    const unsigned short* __restrict__ u, const float* __restrict__ part,
    float* __restrict__ out)
{
    __shared__ float red[16 * 160];
    __shared__ float v_lds[160];
    __shared__ float v1_lds[160];

    const int t    = threadIdx.x;
    const int og   = t & 7, i_l = t >> 3;   // og: o-pair, i_l in 0..127
    const int b    = blockIdx.x;
    const int lane = t & 63, wv = t >> 6;

    const unsigned short* ub = u + (size_t)b * K_ * I_ * O_ + og * 2;
    float acc[K_][2];

    // ---- prologue: s1 = sum over the 72 i-blocks; v1 = squash(s1/K) ----
    if (t < 160) {
        const float* pb = part + (size_t)b * 160 + t;
        float s = 0.f;
#pragma unroll
        for (int xb = 0; xb < NX; xb++)
            s += pb[(size_t)xb * 256 * 160];
        float v = squash_v(s * (1.0f / K_));
        v1_lds[t] = v;
        v_lds[t]  = v;
    }
    __syncthreads();

    // ---- pass 2: logits from v1 ----
    sweep(ub, i_l, v_lds, og, acc);
    block_reduce(acc, red, lane, wv);
    float v12 = 0.f;
    if (t < 160) v12 = v1_lds[t] + squash_v(sum16(red, t));
    __syncthreads();          // all sum16 reads done before v_lds overwrite
    if (t < 160) v_lds[t] = v12;
    __syncthreads();

    // ---- pass 3: logits from v1+v2 (telescoped) ----
    sweep(ub, i_l, v_lds, og, acc);
    block_reduce(acc, red, lane, wv);
    if (t < 160)
        out[(size_t)b * 160 + t] = squash_v(sum16(red, t));
}

// ---------------------------------------------------------------------------
extern "C" void kernel_launch(void* const* d_in, const int* in_sizes, int n_in,
                              void* d_out, int out_size, void* d_ws, size_t ws_size,
                              hipStream_t stream)
{
    const float* x = (const float*)d_in[0];
    const float* w = (const float*)d_in[1];
    float* outp = (float*)d_out;

    float* part = (float*)d_ws;                          // NX*B*K*O f32 = 11.8 MB
    unsigned short* u = (unsigned short*)(part + (size_t)NX * BKO);  // 94.4 MB

    uhat_kernel<<<dim3(72, 4, 5), 256, 0, stream>>>(x, w, u, part);
    route_all<<<B_, 1024, 0, stream>>>(u, part, outp);
}

// Round 14
// 133.756 us; speedup vs baseline: 2.3292x; 1.0387x over previous
//
#include <hip/hip_runtime.h>

#define B_ 256
#define K_ 10
#define I_ 1152
#define O_ 16
#define C_ 8
#define BKO (B_*K_*O_)   // 40960
#define NX 72            // i0 blocks (uhat grid.x)

static __device__ __forceinline__ unsigned short f32_bf16(float f) {
    unsigned int u = __float_as_uint(f);
    u += 0x7FFFu + ((u >> 16) & 1u);           // round-to-nearest-even
    return (unsigned short)(u >> 16);
}

// DPP butterfly add step (full-rate VALU; ctrl is a compile-time const)
template <int CTRL>
static __device__ __forceinline__ float dpp_add(float v) {
    int x = __builtin_amdgcn_update_dpp(0, __float_as_int(v), CTRL, 0xF, 0xF, true);
    return v + __int_as_float(x);
}
// sum over each 16-lane DPP row: xor1, xor2, half-mirror, mirror
static __device__ __forceinline__ float row16_sum(float v) {
    v = dpp_add<0xB1>(v);     // quad_perm(1,0,3,2)  : + lane^1
    v = dpp_add<0x4E>(v);     // quad_perm(2,3,0,1)  : + lane^2
    v = dpp_add<0x141>(v);    // row_half_mirror     : + other quad
    v = dpp_add<0x140>(v);    // row_mirror          : + other half-row
    return v;
}

// ---------------------------------------------------------------------------
// uhat_kernel v6: u[b][k][i][o] = bf16(w·x)  AND pass-1 i-partials into
// part[x][k][b][o] (no atomics).  Fixes vs v5 (72 us):
//  - p_lds rows padded to stride 17: leader-store banks 4*tg%32 -> 2-way, free
//    (was (bb*16+o)%32, tg-invariant -> 16-way, 1.47M conflict cycles)
//  - part relayout [x][k][b][o]: final store is 1024 B contiguous per wave
//    (was b-major stride-640B -> partial lines, write amplification)
//  - u stored as one fused 32 B (2xuint4) per (b,k,i) like round-4's kernel
//    (measured 92 MB writes) instead of split 16 B half-stores.
// grid (72, 4, 5); 256 thr; 4 b per thread (ds_read amortized 4x).
// ---------------------------------------------------------------------------
__global__ __launch_bounds__(256) void uhat_kernel(
    const float* __restrict__ x, const float* __restrict__ w,
    unsigned short* __restrict__ u, float* __restrict__ part)
{
    __shared__ float w_lds[16 * 132];   // [ii][o*8+c], stride 132: 2-way max
    __shared__ float p_lds[2][64 * 17]; // [kk][b_local*17 + o], padded rows
    const int t   = threadIdx.x;
    const int i_l = t & 15, tg = t >> 4;
    const int i0  = blockIdx.x * 16;
    const int b0  = blockIdx.y * 64 + tg * 4;
    const int kb  = blockIdx.z * 2;
    const int i   = i0 + i_l;
    const bool row_leader = (i_l == 0);

    float4 xr[4][2];
#pragma unroll
    for (int bb = 0; bb < 4; bb++) {
        const float4* xp = (const float4*)(x + ((size_t)(b0 + bb) * I_ + i) * C_);
        xr[bb][0] = xp[0];
        xr[bb][1] = xp[1];
    }

#pragma unroll
    for (int kk = 0; kk < 2; kk++) {
        const int k = kb + kk;
        __syncthreads();
        const float4* ws = (const float4*)(w + ((size_t)k * I_ + i0) * O_ * C_);
#pragma unroll
        for (int r = 0; r < 2; r++) {
            int idx = r * 256 + t;               // float4 index in 16x128 slab
            int ii = idx >> 5, rem = idx & 31;
            *(float4*)&w_lds[ii * 132 + rem * 4] = ws[idx];
        }
        __syncthreads();

        unsigned int pk[4][8];
#pragma unroll
        for (int oo = 0; oo < 8; oo++) {         // o-pair index
            float d[4][2];
#pragma unroll
            for (int h = 0; h < 2; h++) {
                const int o = oo * 2 + h;
                const float4 w0 = *(const float4*)&w_lds[i_l * 132 + o * 8];
                const float4 w1 = *(const float4*)&w_lds[i_l * 132 + o * 8 + 4];
#pragma unroll
                for (int bb = 0; bb < 4; bb++) {
                    d[bb][h] = w0.x*xr[bb][0].x + w0.y*xr[bb][0].y
                             + w0.z*xr[bb][0].z + w0.w*xr[bb][0].w
                             + w1.x*xr[bb][1].x + w1.y*xr[bb][1].y
                             + w1.z*xr[bb][1].z + w1.w*xr[bb][1].w;
                }
            }
            // pass-1 fold: i-sum via DPP rows (16 lanes = the 16 i's)
#pragma unroll
            for (int bb = 0; bb < 4; bb++) {
#pragma unroll
                for (int h = 0; h < 2; h++) {
                    const float rs = row16_sum(d[bb][h]);
                    if (row_leader)
                        p_lds[kk][(tg * 4 + bb) * 17 + oo * 2 + h] = rs;
                }
            }
#pragma unroll
            for (int bb = 0; bb < 4; bb++)
                pk[bb][oo] = (unsigned int)f32_bf16(d[bb][0]) |
                             ((unsigned int)f32_bf16(d[bb][1]) << 16);
        }
        // fused 32 B store per (b,k,i)
#pragma unroll
        for (int bb = 0; bb < 4; bb++) {
            unsigned int* dst = (unsigned int*)
                (u + (((size_t)(b0 + bb) * K_ + k) * I_ + i) * O_);
            *(uint4*)(dst)     = make_uint4(pk[bb][0], pk[bb][1], pk[bb][2], pk[bb][3]);
            *(uint4*)(dst + 4) = make_uint4(pk[bb][4], pk[bb][5], pk[bb][6], pk[bb][7]);
        }
    }

    // dense partial store: part[x][k][b][o] — wave writes 1024 B contiguous
    __syncthreads();
    {
        const int bl = t >> 2, o4 = (t & 3) * 4;     // b_local, o-quad
#pragma unroll
        for (int kk = 0; kk < 2; kk++) {
            float4 v;
            v.x = p_lds[kk][bl * 17 + o4 + 0];
            v.y = p_lds[kk][bl * 17 + o4 + 1];
            v.z = p_lds[kk][bl * 17 + o4 + 2];
            v.w = p_lds[kk][bl * 17 + o4 + 3];
            *(float4*)&part[(((size_t)blockIdx.x * K_ + kb + kk) * 256
                             + blockIdx.y * 64 + bl) * O_ + o4] = v;
        }
    }
}

// ---------------------------------------------------------------------------
// sweep (o-pair mapping, 1024-thr block): one routing pass over all i.
// thread: og = t&7 (owns o = og*2, og*2+1), i_l = t>>3 in [0,128); 9 chunks.
// No max-subtraction: |logit| = |sum_16 u*v| is tiny, exp safe in f32.
// ---------------------------------------------------------------------------
static __device__ __forceinline__ void sweep(
    const unsigned short* __restrict__ ub, int i_l,
    const float* __restrict__ v_lds, int og, float acc[K_][2])
{
#pragma unroll
    for (int k = 0; k < K_; k++) { acc[k][0] = 0.f; acc[k][1] = 0.f; }

    unsigned int P[K_], Q[K_];
#pragma unroll
    for (int k = 0; k < K_; k++)
        P[k] = *(const unsigned int*)(ub + ((size_t)k * I_ + i_l) * O_);

#pragma unroll 1                          // keep regs low; body is big enough
    for (int ic = 0; ic < 9; ic++) {
        if (ic + 1 < 9) {
            const int i = (ic + 1) * 128 + i_l;
#pragma unroll
            for (int k = 0; k < K_; k++)
                Q[k] = *(const unsigned int*)(ub + ((size_t)k * I_ + i) * O_);
        }
        float c[K_];
        float Z = 0.f;
#pragma unroll
        for (int k = 0; k < K_; k++) {
            const float f0 = __uint_as_float(P[k] << 16);
            const float f1 = __uint_as_float(P[k] & 0xffff0000u);
            float lk = f0 * v_lds[k * 16 + og * 2]
                     + f1 * v_lds[k * 16 + og * 2 + 1];
            lk += __shfl_xor(lk, 1);
            lk += __shfl_xor(lk, 2);
            lk += __shfl_xor(lk, 4);
            c[k] = __expf(lk);
            Z += c[k];
        }
        const float inv = 1.0f / Z;
#pragma unroll
        for (int k = 0; k < K_; k++) {
            const float ck = c[k] * inv;
            const float f0 = __uint_as_float(P[k] << 16);
            const float f1 = __uint_as_float(P[k] & 0xffff0000u);
            acc[k][0] = fmaf(ck, f0, acc[k][0]);
            acc[k][1] = fmaf(ck, f1, acc[k][1]);
        }
#pragma unroll
        for (int k = 0; k < K_; k++) P[k] = Q[k];
    }
}

// reduce acc over the 8 i-positions of each wave; deposit per-wave sums.
static __device__ __forceinline__ void block_reduce(
    float acc[K_][2], float* __restrict__ red, int lane, int wv)
{
#pragma unroll
    for (int k = 0; k < K_; k++)
#pragma unroll
        for (int j = 0; j < 2; j++) {
            float a = acc[k][j];
            a += __shfl_xor(a, 8); a += __shfl_xor(a, 16); a += __shfl_xor(a, 32);
            acc[k][j] = a;
        }
    if (lane < 8) {
#pragma unroll
        for (int k = 0; k < K_; k++)
            *(float2*)&red[wv * 160 + k * 16 + lane * 2] =
                make_float2(acc[k][0], acc[k][1]);
    }
    __syncthreads();
}

// sum the 16 per-wave partials for element t (t < 160)
static __device__ __forceinline__ float sum16(const float* __restrict__ red, int t)
{
    float s = 0.f;
#pragma unroll
    for (int wgi = 0; wgi < 16; wgi++) s += red[wgi * 160 + t];
    return s;
}

// squash for element t<160: 16-lane o-group norm reduce
static __device__ __forceinline__ float squash_v(float s) {
    float n2 = s * s;
    n2 += __shfl_xor(n2, 1); n2 += __shfl_xor(n2, 2);
    n2 += __shfl_xor(n2, 4); n2 += __shfl_xor(n2, 8);
    const float norm = sqrtf(n2);
    return s * (n2 / (1.0f + n2) / (norm + 1e-9f));
}

// ---------------------------------------------------------------------------
// route_all v6: passes 2+3 only; pass 1 from the part tensor [x][k][b][o].
// grid (256), 1024 thr.  Prologue: s1 = sum_x part[x][k][b], v1 = squash/K.
// 2 u sweeps instead of 3 (u LLC-hot after uhat: round-13 evidence put this
// kernel + gaps at ~24 us).
// ---------------------------------------------------------------------------
__global__ __launch_bounds__(1024) void route_all(
    const unsigned short* __restrict__ u, const float* __restrict__ part,
    float* __restrict__ out)
{
    __shared__ float red[16 * 160];
    __shared__ float v_lds[160];
    __shared__ float v1_lds[160];

    const int t    = threadIdx.x;
    const int og   = t & 7, i_l = t >> 3;   // og: o-pair, i_l in 0..127
    const int b    = blockIdx.x;
    const int lane = t & 63, wv = t >> 6;

    const unsigned short* ub = u + (size_t)b * K_ * I_ * O_ + og * 2;
    float acc[K_][2];

    // ---- prologue: s1 = sum over the 72 i-blocks; v1 = squash(s1/K) ----
    if (t < 160) {
        const int k = t >> 4, o = t & 15;
        const float* pb = part + ((size_t)k * 256 + b) * O_ + o;
        float s = 0.f;
#pragma unroll
        for (int xb = 0; xb < NX; xb++)
            s += pb[(size_t)xb * BKO];
        float v = squash_v(s * (1.0f / K_));
        v1_lds[t] = v;
        v_lds[t]  = v;
    }
    __syncthreads();

    // ---- pass 2: logits from v1 ----
    sweep(ub, i_l, v_lds, og, acc);
    block_reduce(acc, red, lane, wv);
    float v12 = 0.f;
    if (t < 160) v12 = v1_lds[t] + squash_v(sum16(red, t));
    __syncthreads();          // all sum16 reads done before v_lds overwrite
    if (t < 160) v_lds[t] = v12;
    __syncthreads();

    // ---- pass 3: logits from v1+v2 (telescoped) ----
    sweep(ub, i_l, v_lds, og, acc);
    block_reduce(acc, red, lane, wv);
    if (t < 160)
        out[(size_t)b * 160 + t] = squash_v(sum16(red, t));
}

// ---------------------------------------------------------------------------
extern "C" void kernel_launch(void* const* d_in, const int* in_sizes, int n_in,
                              void* d_out, int out_size, void* d_ws, size_t ws_size,
                              hipStream_t stream)
{
    const float* x = (const float*)d_in[0];
    const float* w = (const float*)d_in[1];
    float* outp = (float*)d_out;

    float* part = (float*)d_ws;                          // NX*BKO f32 = 11.8 MB
    unsigned short* u = (unsigned short*)(part + (size_t)NX * BKO);  // 94.4 MB

    uhat_kernel<<<dim3(72, 4, 5), 256, 0, stream>>>(x, w, u, part);
    route_all<<<B_, 1024, 0, stream>>>(u, part, outp);
}

// Round 15
// 126.272 us; speedup vs baseline: 2.4673x; 1.0593x over previous
//
#include <hip/hip_runtime.h>

#define B_ 256
#define K_ 10
#define I_ 1152
#define O_ 16
#define C_ 8
#define BKO (B_*K_*O_)   // 40960
#define NX 72            // i0 blocks (uhat grid.x)

static __device__ __forceinline__ unsigned short f32_bf16(float f) {
    unsigned int u = __float_as_uint(f);
    u += 0x7FFFu + ((u >> 16) & 1u);           // round-to-nearest-even
    return (unsigned short)(u >> 16);
}

// DPP butterfly add step (full-rate VALU; ctrl is a compile-time const)
template <int CTRL>
static __device__ __forceinline__ float dpp_add(float v) {
    int x = __builtin_amdgcn_update_dpp(0, __float_as_int(v), CTRL, 0xF, 0xF, true);
    return v + __int_as_float(x);
}
// sum over each 16-lane DPP row: xor1, xor2, half-mirror, mirror
static __device__ __forceinline__ float row16_sum(float v) {
    v = dpp_add<0xB1>(v);     // quad_perm(1,0,3,2)  : + lane^1
    v = dpp_add<0x4E>(v);     // quad_perm(2,3,0,1)  : + lane^2
    v = dpp_add<0x141>(v);    // row_half_mirror     : + other quad
    v = dpp_add<0x140>(v);    // row_mirror          : + other half-row
    return v;
}

// ---------------------------------------------------------------------------
// uhat_kernel v7: u[b][k][i][o] = bf16(w·x) + pass-1 partials part[x][k][b][o].
// grid (72, 4, 10): ONE k per block (v6 had 2) -> 2880 blocks ≈ 11/CU for
// store/compute overlap (v6 ran ~2x over its write floor at 5.6 blocks/CU).
// 256 thr; 4 b per thread (each w ds_read feeds 4 b's of FMAs).
// ---------------------------------------------------------------------------
__global__ __launch_bounds__(256) void uhat_kernel(
    const float* __restrict__ x, const float* __restrict__ w,
    unsigned short* __restrict__ u, float* __restrict__ part)
{
    __shared__ float w_lds[16 * 132];   // [ii][o*8+c], stride 132: 2-way max
    __shared__ float p_lds[64 * 17];    // [b_local*17 + o], padded rows
    const int t   = threadIdx.x;
    const int i_l = t & 15, tg = t >> 4;
    const int i0  = blockIdx.x * 16;
    const int b0  = blockIdx.y * 64 + tg * 4;
    const int k   = blockIdx.z;
    const int i   = i0 + i_l;
    const bool row_leader = (i_l == 0);

    float4 xr[4][2];
#pragma unroll
    for (int bb = 0; bb < 4; bb++) {
        const float4* xp = (const float4*)(x + ((size_t)(b0 + bb) * I_ + i) * C_);
        xr[bb][0] = xp[0];
        xr[bb][1] = xp[1];
    }

    {
        const float4* ws = (const float4*)(w + ((size_t)k * I_ + i0) * O_ * C_);
#pragma unroll
        for (int r = 0; r < 2; r++) {
            int idx = r * 256 + t;               // float4 index in 16x128 slab
            int ii = idx >> 5, rem = idx & 31;
            *(float4*)&w_lds[ii * 132 + rem * 4] = ws[idx];
        }
    }
    __syncthreads();

    unsigned int pk[4][8];
#pragma unroll
    for (int oo = 0; oo < 8; oo++) {             // o-pair index
        float d[4][2];
#pragma unroll
        for (int h = 0; h < 2; h++) {
            const int o = oo * 2 + h;
            const float4 w0 = *(const float4*)&w_lds[i_l * 132 + o * 8];
            const float4 w1 = *(const float4*)&w_lds[i_l * 132 + o * 8 + 4];
#pragma unroll
            for (int bb = 0; bb < 4; bb++) {
                d[bb][h] = w0.x*xr[bb][0].x + w0.y*xr[bb][0].y
                         + w0.z*xr[bb][0].z + w0.w*xr[bb][0].w
                         + w1.x*xr[bb][1].x + w1.y*xr[bb][1].y
                         + w1.z*xr[bb][1].z + w1.w*xr[bb][1].w;
            }
        }
        // pass-1 fold: i-sum via DPP rows (16 lanes = the 16 i's)
#pragma unroll
        for (int bb = 0; bb < 4; bb++) {
#pragma unroll
            for (int h = 0; h < 2; h++) {
                const float rs = row16_sum(d[bb][h]);
                if (row_leader)
                    p_lds[(tg * 4 + bb) * 17 + oo * 2 + h] = rs;
            }
        }
#pragma unroll
        for (int bb = 0; bb < 4; bb++)
            pk[bb][oo] = (unsigned int)f32_bf16(d[bb][0]) |
                         ((unsigned int)f32_bf16(d[bb][1]) << 16);
    }
    // fused 32 B u store per (b,k,i)
#pragma unroll
    for (int bb = 0; bb < 4; bb++) {
        unsigned int* dst = (unsigned int*)
            (u + (((size_t)(b0 + bb) * K_ + k) * I_ + i) * O_);
        *(uint4*)(dst)     = make_uint4(pk[bb][0], pk[bb][1], pk[bb][2], pk[bb][3]);
        *(uint4*)(dst + 4) = make_uint4(pk[bb][4], pk[bb][5], pk[bb][6], pk[bb][7]);
    }

    // dense partial store: part[x][k][b][o] — wave writes 1024 B contiguous
    __syncthreads();
    {
        const int bl = t >> 2, o4 = (t & 3) * 4;     // b_local, o-quad
        float4 v;
        v.x = p_lds[bl * 17 + o4 + 0];
        v.y = p_lds[bl * 17 + o4 + 1];
        v.z = p_lds[bl * 17 + o4 + 2];
        v.w = p_lds[bl * 17 + o4 + 3];
        *(float4*)&part[(((size_t)blockIdx.x * K_ + k) * 256
                         + blockIdx.y * 64 + bl) * O_ + o4] = v;
    }
}

// ---------------------------------------------------------------------------
// sweep v7 (o-quad mapping, 512-thr block): one routing pass over all i.
// thread: og = t&3 (owns o = og*4..og*4+3, uint2 8 B loads -> 512 B per
// wave-VMEM, half the VMEM instr/byte of the o-pair version), i_l = t>>2 in
// [0,128); 9 chunks.  ~100 VGPR, under the 128 cap for 512-thr blocks
// (cap rule from r7/8/10: 512 / waves-per-SIMD-at-2-blocks/CU).
// ---------------------------------------------------------------------------
static __device__ __forceinline__ void sweep(
    const unsigned short* __restrict__ ub, int i_l,
    const float* __restrict__ v_lds, int og, float acc[K_][4])
{
#pragma unroll
    for (int k = 0; k < K_; k++)
#pragma unroll
        for (int j = 0; j < 4; j++) acc[k][j] = 0.f;

    uint2 P[K_], Q[K_];
#pragma unroll
    for (int k = 0; k < K_; k++)
        P[k] = *(const uint2*)(ub + ((size_t)k * I_ + i_l) * O_);

#pragma unroll 1                          // keep regs low; body is big enough
    for (int ic = 0; ic < 9; ic++) {
        if (ic + 1 < 9) {
            const int i = (ic + 1) * 128 + i_l;
#pragma unroll
            for (int k = 0; k < K_; k++)
                Q[k] = *(const uint2*)(ub + ((size_t)k * I_ + i) * O_);
        }
        float c[K_];
        float Z = 0.f;
#pragma unroll
        for (int k = 0; k < K_; k++) {
            const float f0 = __uint_as_float(P[k].x << 16);
            const float f1 = __uint_as_float(P[k].x & 0xffff0000u);
            const float f2 = __uint_as_float(P[k].y << 16);
            const float f3 = __uint_as_float(P[k].y & 0xffff0000u);
            const float* vk = &v_lds[k * 16 + og * 4];
            float lk = f0 * vk[0] + f1 * vk[1] + f2 * vk[2] + f3 * vk[3];
            lk += __shfl_xor(lk, 1);
            lk += __shfl_xor(lk, 2);
            c[k] = __expf(lk);
            Z += c[k];
        }
        const float inv = 1.0f / Z;
#pragma unroll
        for (int k = 0; k < K_; k++) {
            const float ck = c[k] * inv;
            acc[k][0] = fmaf(ck, __uint_as_float(P[k].x << 16),        acc[k][0]);
            acc[k][1] = fmaf(ck, __uint_as_float(P[k].x & 0xffff0000u), acc[k][1]);
            acc[k][2] = fmaf(ck, __uint_as_float(P[k].y << 16),        acc[k][2]);
            acc[k][3] = fmaf(ck, __uint_as_float(P[k].y & 0xffff0000u), acc[k][3]);
        }
#pragma unroll
        for (int k = 0; k < K_; k++) P[k] = Q[k];
    }
}

// reduce acc over the 16 i-positions of each wave; deposit per-wave sums.
static __device__ __forceinline__ void block_reduce(
    float acc[K_][4], float* __restrict__ red, int lane, int wv)
{
#pragma unroll
    for (int k = 0; k < K_; k++)
#pragma unroll
        for (int j = 0; j < 4; j++) {
            float a = acc[k][j];
            a += __shfl_xor(a, 4);  a += __shfl_xor(a, 8);
            a += __shfl_xor(a, 16); a += __shfl_xor(a, 32);
            acc[k][j] = a;
        }
    if (lane < 4) {
#pragma unroll
        for (int k = 0; k < K_; k++)
            *(float4*)&red[wv * 160 + k * 16 + lane * 4] =
                make_float4(acc[k][0], acc[k][1], acc[k][2], acc[k][3]);
    }
    __syncthreads();
}

// sum the 8 per-wave partials for element t (t < 160)
static __device__ __forceinline__ float sum8(const float* __restrict__ red, int t)
{
    float s = 0.f;
#pragma unroll
    for (int wgi = 0; wgi < 8; wgi++) s += red[wgi * 160 + t];
    return s;
}

// squash for element t<160: 16-lane o-group norm reduce
static __device__ __forceinline__ float squash_v(float s) {
    float n2 = s * s;
    n2 += __shfl_xor(n2, 1); n2 += __shfl_xor(n2, 2);
    n2 += __shfl_xor(n2, 4); n2 += __shfl_xor(n2, 8);
    const float norm = sqrtf(n2);
    return s * (n2 / (1.0f + n2) / (norm + 1e-9f));
}

// ---------------------------------------------------------------------------
// route_all v7: passes 2+3; pass 1 from part[x][k][b][o].
// grid (256), 512 thr (8 waves).  Prologue: s1 = sum_x part, v1 = squash/K.
// ---------------------------------------------------------------------------
__global__ __launch_bounds__(512) void route_all(
    const unsigned short* __restrict__ u, const float* __restrict__ part,
    float* __restrict__ out)
{
    __shared__ float red[8 * 160];
    __shared__ float v_lds[160];
    __shared__ float v1_lds[160];

    const int t    = threadIdx.x;
    const int og   = t & 3, i_l = t >> 2;   // og: o-quad, i_l in 0..127
    const int b    = blockIdx.x;
    const int lane = t & 63, wv = t >> 6;

    const unsigned short* ub = u + (size_t)b * K_ * I_ * O_ + og * 4;
    float acc[K_][4];

    // ---- prologue: s1 = sum over the 72 i-blocks; v1 = squash(s1/K) ----
    if (t < 160) {
        const int k = t >> 4, o = t & 15;
        const float* pb = part + ((size_t)k * 256 + b) * O_ + o;
        float s = 0.f;
#pragma unroll
        for (int xb = 0; xb < NX; xb++)
            s += pb[(size_t)xb * BKO];
        float v = squash_v(s * (1.0f / K_));
        v1_lds[t] = v;
        v_lds[t]  = v;
    }
    __syncthreads();

    // ---- pass 2: logits from v1 ----
    sweep(ub, i_l, v_lds, og, acc);
    block_reduce(acc, red, lane, wv);
    float v12 = 0.f;
    if (t < 160) v12 = v1_lds[t] + squash_v(sum8(red, t));
    __syncthreads();          // all sum8 reads done before v_lds overwrite
    if (t < 160) v_lds[t] = v12;
    __syncthreads();

    // ---- pass 3: logits from v1+v2 (telescoped) ----
    sweep(ub, i_l, v_lds, og, acc);
    block_reduce(acc, red, lane, wv);
    if (t < 160)
        out[(size_t)b * 160 + t] = squash_v(sum8(red, t));
}

// ---------------------------------------------------------------------------
extern "C" void kernel_launch(void* const* d_in, const int* in_sizes, int n_in,
                              void* d_out, int out_size, void* d_ws, size_t ws_size,
                              hipStream_t stream)
{
    const float* x = (const float*)d_in[0];
    const float* w = (const float*)d_in[1];
    float* outp = (float*)d_out;

    float* part = (float*)d_ws;                          // NX*BKO f32 = 11.8 MB
    unsigned short* u = (unsigned short*)(part + (size_t)NX * BKO);  // 94.4 MB

    uhat_kernel<<<dim3(72, 4, 10), 256, 0, stream>>>(x, w, u, part);
    route_all<<<B_, 512, 0, stream>>>(u, part, outp);
}

// Round 16
// 123.523 us; speedup vs baseline: 2.5222x; 1.0223x over previous
//
#include <hip/hip_runtime.h>

#define B_ 256
#define K_ 10
#define I_ 1152
#define O_ 16
#define C_ 8
#define BKO (B_*K_*O_)   // 40960
#define NX 72            // i0 blocks (uhat grid.x)

static __device__ __forceinline__ unsigned short f32_bf16(float f) {
    unsigned int u = __float_as_uint(f);
    u += 0x7FFFu + ((u >> 16) & 1u);           // round-to-nearest-even
    return (unsigned short)(u >> 16);
}

// DPP butterfly add step (full-rate VALU; ctrl is a compile-time const)
template <int CTRL>
static __device__ __forceinline__ float dpp_add(float v) {
    int x = __builtin_amdgcn_update_dpp(0, __float_as_int(v), CTRL, 0xF, 0xF, true);
    return v + __int_as_float(x);
}
// sum over each 16-lane DPP row: xor1, xor2, half-mirror, mirror
static __device__ __forceinline__ float row16_sum(float v) {
    v = dpp_add<0xB1>(v);     // quad_perm(1,0,3,2)  : + lane^1
    v = dpp_add<0x4E>(v);     // quad_perm(2,3,0,1)  : + lane^2
    v = dpp_add<0x141>(v);    // row_half_mirror     : + other quad
    v = dpp_add<0x140>(v);    // row_mirror          : + other half-row
    return v;
}
// sum over the 4 lanes of each quad (the og group) — VALU-rate, no LDS pipe
static __device__ __forceinline__ float quad4_sum(float v) {
    v = dpp_add<0xB1>(v);     // + lane^1
    v = dpp_add<0x4E>(v);     // + lane^2
    return v;
}

// ---------------------------------------------------------------------------
// uhat_kernel v7 (FROZEN from round 15): u[b][k][i][o] = bf16(w·x) + pass-1
// partials part[x][k][b][o].  grid (72, 4, 10); 256 thr; 4 b per thread.
// ---------------------------------------------------------------------------
__global__ __launch_bounds__(256) void uhat_kernel(
    const float* __restrict__ x, const float* __restrict__ w,
    unsigned short* __restrict__ u, float* __restrict__ part)
{
    __shared__ float w_lds[16 * 132];   // [ii][o*8+c], stride 132: 2-way max
    __shared__ float p_lds[64 * 17];    // [b_local*17 + o], padded rows
    const int t   = threadIdx.x;
    const int i_l = t & 15, tg = t >> 4;
    const int i0  = blockIdx.x * 16;
    const int b0  = blockIdx.y * 64 + tg * 4;
    const int k   = blockIdx.z;
    const int i   = i0 + i_l;
    const bool row_leader = (i_l == 0);

    float4 xr[4][2];
#pragma unroll
    for (int bb = 0; bb < 4; bb++) {
        const float4* xp = (const float4*)(x + ((size_t)(b0 + bb) * I_ + i) * C_);
        xr[bb][0] = xp[0];
        xr[bb][1] = xp[1];
    }

    {
        const float4* ws = (const float4*)(w + ((size_t)k * I_ + i0) * O_ * C_);
#pragma unroll
        for (int r = 0; r < 2; r++) {
            int idx = r * 256 + t;               // float4 index in 16x128 slab
            int ii = idx >> 5, rem = idx & 31;
            *(float4*)&w_lds[ii * 132 + rem * 4] = ws[idx];
        }
    }
    __syncthreads();

    unsigned int pk[4][8];
#pragma unroll
    for (int oo = 0; oo < 8; oo++) {             // o-pair index
        float d[4][2];
#pragma unroll
        for (int h = 0; h < 2; h++) {
            const int o = oo * 2 + h;
            const float4 w0 = *(const float4*)&w_lds[i_l * 132 + o * 8];
            const float4 w1 = *(const float4*)&w_lds[i_l * 132 + o * 8 + 4];
#pragma unroll
            for (int bb = 0; bb < 4; bb++) {
                d[bb][h] = w0.x*xr[bb][0].x + w0.y*xr[bb][0].y
                         + w0.z*xr[bb][0].z + w0.w*xr[bb][0].w
                         + w1.x*xr[bb][1].x + w1.y*xr[bb][1].y
                         + w1.z*xr[bb][1].z + w1.w*xr[bb][1].w;
            }
        }
        // pass-1 fold: i-sum via DPP rows (16 lanes = the 16 i's)
#pragma unroll
        for (int bb = 0; bb < 4; bb++) {
#pragma unroll
            for (int h = 0; h < 2; h++) {
                const float rs = row16_sum(d[bb][h]);
                if (row_leader)
                    p_lds[(tg * 4 + bb) * 17 + oo * 2 + h] = rs;
            }
        }
#pragma unroll
        for (int bb = 0; bb < 4; bb++)
            pk[bb][oo] = (unsigned int)f32_bf16(d[bb][0]) |
                         ((unsigned int)f32_bf16(d[bb][1]) << 16);
    }
    // fused 32 B u store per (b,k,i)
#pragma unroll
    for (int bb = 0; bb < 4; bb++) {
        unsigned int* dst = (unsigned int*)
            (u + (((size_t)(b0 + bb) * K_ + k) * I_ + i) * O_);
        *(uint4*)(dst)     = make_uint4(pk[bb][0], pk[bb][1], pk[bb][2], pk[bb][3]);
        *(uint4*)(dst + 4) = make_uint4(pk[bb][4], pk[bb][5], pk[bb][6], pk[bb][7]);
    }

    // dense partial store: part[x][k][b][o] — wave writes 1024 B contiguous
    __syncthreads();
    {
        const int bl = t >> 2, o4 = (t & 3) * 4;     // b_local, o-quad
        float4 v;
        v.x = p_lds[bl * 17 + o4 + 0];
        v.y = p_lds[bl * 17 + o4 + 1];
        v.z = p_lds[bl * 17 + o4 + 2];
        v.w = p_lds[bl * 17 + o4 + 3];
        *(float4*)&part[(((size_t)blockIdx.x * K_ + k) * 256
                         + blockIdx.y * 64 + bl) * O_ + o4] = v;
    }
}

// ---------------------------------------------------------------------------
// sweep v8 (o-quad, 512-thr block, DPP logit reduce): one pass over all i.
// thread: og = t&3 (o = og*4..og*4+3, uint2 8 B loads), i_l = t>>2 in
// [0,128); 9 chunks.  The o-sum for logits is a quad-lane sum -> DPP
// quad_perm adds (VALU rate) instead of ds_bpermute shuffles (LDS-pipe
// ~30-50 cyc each, 20/chunk on the critical path at only ~2 waves/SIMD).
// ---------------------------------------------------------------------------
static __device__ __forceinline__ void sweep(
    const unsigned short* __restrict__ ub, int i_l,
    const float* __restrict__ v_lds, int og, float acc[K_][4])
{
#pragma unroll
    for (int k = 0; k < K_; k++)
#pragma unroll
        for (int j = 0; j < 4; j++) acc[k][j] = 0.f;

    uint2 P[K_], Q[K_];
#pragma unroll
    for (int k = 0; k < K_; k++)
        P[k] = *(const uint2*)(ub + ((size_t)k * I_ + i_l) * O_);

#pragma unroll 1                          // keep regs low; body is big enough
    for (int ic = 0; ic < 9; ic++) {
        if (ic + 1 < 9) {
            const int i = (ic + 1) * 128 + i_l;
#pragma unroll
            for (int k = 0; k < K_; k++)
                Q[k] = *(const uint2*)(ub + ((size_t)k * I_ + i) * O_);
        }
        float c[K_];
        float Z = 0.f;
#pragma unroll
        for (int k = 0; k < K_; k++) {
            const float f0 = __uint_as_float(P[k].x << 16);
            const float f1 = __uint_as_float(P[k].x & 0xffff0000u);
            const float f2 = __uint_as_float(P[k].y << 16);
            const float f3 = __uint_as_float(P[k].y & 0xffff0000u);
            const float* vk = &v_lds[k * 16 + og * 4];
            float lk = f0 * vk[0] + f1 * vk[1] + f2 * vk[2] + f3 * vk[3];
            lk = quad4_sum(lk);           // DPP, VALU-rate (was 2x shfl_xor)
            c[k] = __expf(lk);
            Z += c[k];
        }
        const float inv = 1.0f / Z;
#pragma unroll
        for (int k = 0; k < K_; k++) {
            const float ck = c[k] * inv;
            acc[k][0] = fmaf(ck, __uint_as_float(P[k].x << 16),        acc[k][0]);
            acc[k][1] = fmaf(ck, __uint_as_float(P[k].x & 0xffff0000u), acc[k][1]);
            acc[k][2] = fmaf(ck, __uint_as_float(P[k].y << 16),        acc[k][2]);
            acc[k][3] = fmaf(ck, __uint_as_float(P[k].y & 0xffff0000u), acc[k][3]);
        }
#pragma unroll
        for (int k = 0; k < K_; k++) P[k] = Q[k];
    }
}

// reduce acc over the 16 i-positions of each wave; deposit per-wave sums.
// (runs once per sweep — shfl latency acceptable here; mirrors can't be used
// because lanes alternate og within rows)
static __device__ __forceinline__ void block_reduce(
    float acc[K_][4], float* __restrict__ red, int lane, int wv)
{
#pragma unroll
    for (int k = 0; k < K_; k++)
#pragma unroll
        for (int j = 0; j < 4; j++) {
            float a = acc[k][j];
            a += __shfl_xor(a, 4);  a += __shfl_xor(a, 8);
            a += __shfl_xor(a, 16); a += __shfl_xor(a, 32);
            acc[k][j] = a;
        }
    if (lane < 4) {
#pragma unroll
        for (int k = 0; k < K_; k++)
            *(float4*)&red[wv * 160 + k * 16 + lane * 4] =
                make_float4(acc[k][0], acc[k][1], acc[k][2], acc[k][3]);
    }
    __syncthreads();
}

// sum the 8 per-wave partials for element t (t < 160)
static __device__ __forceinline__ float sum8(const float* __restrict__ red, int t)
{
    float s = 0.f;
#pragma unroll
    for (int wgi = 0; wgi < 8; wgi++) s += red[wgi * 160 + t];
    return s;
}

// squash for element t<160: 16-lane o-group norm reduce
static __device__ __forceinline__ float squash_v(float s) {
    float n2 = s * s;
    n2 += __shfl_xor(n2, 1); n2 += __shfl_xor(n2, 2);
    n2 += __shfl_xor(n2, 4); n2 += __shfl_xor(n2, 8);
    const float norm = sqrtf(n2);
    return s * (n2 / (1.0f + n2) / (norm + 1e-9f));
}

// ---------------------------------------------------------------------------
// route_all v8: passes 2+3; pass 1 from part[x][k][b][o].
// grid (256), 512 thr (8 waves).  Prologue: s1 = sum_x part, v1 = squash/K.
// ---------------------------------------------------------------------------
__global__ __launch_bounds__(512) void route_all(
    const unsigned short* __restrict__ u, const float* __restrict__ part,
    float* __restrict__ out)
{
    __shared__ float red[8 * 160];
    __shared__ float v_lds[160];
    __shared__ float v1_lds[160];

    const int t    = threadIdx.x;
    const int og   = t & 3, i_l = t >> 2;   // og: o-quad, i_l in 0..127
    const int b    = blockIdx.x;
    const int lane = t & 63, wv = t >> 6;

    const unsigned short* ub = u + (size_t)b * K_ * I_ * O_ + og * 4;
    float acc[K_][4];

    // ---- prologue: s1 = sum over the 72 i-blocks; v1 = squash(s1/K) ----
    if (t < 160) {
        const int k = t >> 4, o = t & 15;
        const float* pb = part + ((size_t)k * 256 + b) * O_ + o;
        float s = 0.f;
#pragma unroll
        for (int xb = 0; xb < NX; xb++)
            s += pb[(size_t)xb * BKO];
        float v = squash_v(s * (1.0f / K_));
        v1_lds[t] = v;
        v_lds[t]  = v;
    }
    __syncthreads();

    // ---- pass 2: logits from v1 ----
    sweep(ub, i_l, v_lds, og, acc);
    block_reduce(acc, red, lane, wv);
    float v12 = 0.f;
    if (t < 160) v12 = v1_lds[t] + squash_v(sum8(red, t));
    __syncthreads();          // all sum8 reads done before v_lds overwrite
    if (t < 160) v_lds[t] = v12;
    __syncthreads();

    // ---- pass 3: logits from v1+v2 (telescoped) ----
    sweep(ub, i_l, v_lds, og, acc);
    block_reduce(acc, red, lane, wv);
    if (t < 160)
        out[(size_t)b * 160 + t] = squash_v(sum8(red, t));
}

// ---------------------------------------------------------------------------
extern "C" void kernel_launch(void* const* d_in, const int* in_sizes, int n_in,
                              void* d_out, int out_size, void* d_ws, size_t ws_size,
                              hipStream_t stream)
{
    const float* x = (const float*)d_in[0];
    const float* w = (const float*)d_in[1];
    float* outp = (float*)d_out;

    float* part = (float*)d_ws;                          // NX*BKO f32 = 11.8 MB
    unsigned short* u = (unsigned short*)(part + (size_t)NX * BKO);  // 94.4 MB

    uhat_kernel<<<dim3(72, 4, 10), 256, 0, stream>>>(x, w, u, part);
    route_all<<<B_, 512, 0, stream>>>(u, part, outp);
}